// Round 4
// baseline (417.605 us; speedup 1.0000x reference)
//
#include <hip/hip_runtime.h>
#include <math.h>

// B=4, C=64, H=W=64, N=4096, NPIX=16384. All fp32 in/out.
// Pixel-major [pix][ch] bf16 hi/lo pipeline. ws (floats), footprint 5M+256:
//  A ws+0M..1M : xT hi|lo -> x1T hi|lo -> zT hi|lo
//  B ws+1M..2M : c1T fp32 -> yT hi|lo
//  C ws+2M..3M : thT hi|lo -> c2T fp32
//  D ws+3M..4M : phT hi|lo
//  E ws+4M..4.5M : g16 (bf16 [B][C][N])
//  wp ws+4.5M : prepped weights; part ws+5M-65536 (512 blk x 64 ch x 2); stats ws+5M

typedef __attribute__((ext_vector_type(8))) short short8;
typedef __attribute__((ext_vector_type(4))) float f32x4;

__device__ __forceinline__ ushort f2bf(float x) {
    unsigned u = __float_as_uint(x);
    unsigned r = (u + 0x7FFFu + ((u >> 16) & 1u)) >> 16;  // RNE
    return (ushort)r;
}
__device__ __forceinline__ float bf2f(ushort h) {
    return __uint_as_float(((unsigned)h) << 16);
}

// ---------------------------------------------------------------------------
// prep_all: blocks <256: x [B][C][N] fp32 -> xT [pix][ch] bf16 hi/lo.
// blocks >=256: weight prep (5x 3x3 sets -> [tap][co][ci] hi/lo, + 1x1).
// ---------------------------------------------------------------------------
__global__ __launch_bounds__(256) void prep_all_k(
    const float* __restrict__ x, ushort* __restrict__ xh,
    ushort* __restrict__ xl,
    const float* __restrict__ w0, const float* __restrict__ w1,
    const float* __restrict__ w2, const float* __restrict__ w3,
    const float* __restrict__ w4, const float* __restrict__ w5,
    ushort* __restrict__ wbase)
{
    __shared__ __align__(16) float T[64 * 68];
    const int blk = blockIdx.x, t = threadIdx.x;
    if (blk < 256) {
        const int b = blk >> 6, n0 = (blk & 63) << 6;
        for (int p = t; p < 1024; p += 256) {
            int c = p >> 4, n4 = (p & 15) << 2;
            *(float4*)&T[c * 68 + n4] =
                *(const float4*)&x[(((size_t)(b * 64 + c)) << 12) + n0 + n4];
        }
        __syncthreads();
        for (int p = t; p < 1024; p += 256) {
            int n = p >> 4, c4 = (p & 15) << 2;
            size_t off = (((size_t)(b * 4096 + n0 + n)) << 6) + c4;
            ushort4 hi, lo;
            float v;
            v = T[(c4 + 0) * 68 + n]; hi.x = f2bf(v); lo.x = f2bf(v - bf2f(hi.x));
            v = T[(c4 + 1) * 68 + n]; hi.y = f2bf(v); lo.y = f2bf(v - bf2f(hi.y));
            v = T[(c4 + 2) * 68 + n]; hi.z = f2bf(v); lo.z = f2bf(v - bf2f(hi.z));
            v = T[(c4 + 3) * 68 + n]; hi.w = f2bf(v); lo.w = f2bf(v - bf2f(hi.w));
            *(ushort4*)&xh[off] = hi;
            *(ushort4*)&xl[off] = lo;
        }
    } else {
        const float* W[6] = {w0, w1, w2, w3, w4, w5};
        int q = blk - 256;
        if (q < 720) {
            int s = q / 144, bi = q - s * 144;
            int idx = bi * 256 + t;
            if (idx >= 36864) return;
            int co = idx / 576;
            int r = idx - co * 576;
            int ci = r / 9;
            int tap = r - ci * 9;
            float v = W[s][idx];
            ushort* hi = wbase + (size_t)s * 73728;
            ushort* lo = hi + 36864;
            int off = tap * 4096 + co * 64 + ci;
            ushort h = f2bf(v);
            hi[off] = h;
            lo[off] = f2bf(v - bf2f(h));
        } else {
            int idx = (q - 720) * 256 + t;
            if (idx >= 4096) return;
            float v = W[5][idx];
            ushort* hi = wbase + 5 * 73728;
            ushort* lo = hi + 4096;
            ushort h = f2bf(v);
            hi[idx] = h;
            lo[idx] = f2bf(v - bf2f(h));
        }
    }
}

// ---------------------------------------------------------------------------
// MFMA 3x3 conv, 9 shifted GEMM taps. Block = 32 pix x 64 co (grid 512 ->
// 2 blocks/CU). 4 waves, wave tile 16pix x 32co. No LDS in main loop; A/B
// frags stream from global. hi/lo compensated (3 MFMA/product).
// MODE 0: fp32 out [pix][co] + fused BN partial stats -> part[blk][ch].
// MODE 1 (NOUT=3): theta/phi -> hi/lo [pix][co]; g -> bf16 [B][co][n].
// ---------------------------------------------------------------------------
template <int NOUT, int MODE>
__global__ __launch_bounds__(256) void conv_mfma_k(
    const ushort* __restrict__ Ah, const ushort* __restrict__ Al,
    const ushort* __restrict__ w0h, const ushort* __restrict__ w0l,
    const ushort* __restrict__ w1h, const ushort* __restrict__ w1l,
    const ushort* __restrict__ w2h, const ushort* __restrict__ w2l,
    const float* __restrict__ b0, const float* __restrict__ b1,
    const float* __restrict__ b2,
    float* __restrict__ outF, float* __restrict__ part,
    ushort* __restrict__ o0h, ushort* __restrict__ o0l,
    ushort* __restrict__ o1h, ushort* __restrict__ o1l,
    ushort* __restrict__ o2t)
{
    __shared__ float redS[4][64], redSS[4][64];
    const int t = threadIdx.x, lane = t & 63, wv = t >> 6;
    const int quad = lane >> 4, l15 = lane & 15;
    const int P0 = blockIdx.x << 5;
    const int row = P0 >> 6;     // b*64 + h
    const int h = row & 63;
    const int wbase = (P0 & 63) + ((wv >> 1) << 4);  // lane-0 w coord
    const int chalf = (wv & 1) << 5;

    const ushort* wh[3] = {w0h, w1h, w2h};
    const ushort* wl[3] = {w0l, w1l, w2l};

    f32x4 acc[NOUT][2];
#pragma unroll
    for (int o = 0; o < NOUT; ++o)
#pragma unroll
        for (int cb = 0; cb < 2; ++cb)
#pragma unroll
            for (int j = 0; j < 4; ++j) acc[o][cb][j] = 0.f;

#pragma unroll
    for (int dh = -1; dh <= 1; ++dh) {
        if ((unsigned)(h + dh) >= 64u) continue;  // block-uniform
#pragma unroll
        for (int dw = -1; dw <= 1; ++dw) {
            const int tap = (dh + 1) * 3 + (dw + 1);
#pragma unroll
            for (int kc = 0; kc < 2; ++kc) {
                const int k0 = kc * 32 + quad * 8;
                const int sw = wbase + l15 + dw;
                short8 aH = {0, 0, 0, 0, 0, 0, 0, 0};
                short8 aL = {0, 0, 0, 0, 0, 0, 0, 0};
                if ((unsigned)sw < 64u) {
                    size_t off = (((size_t)(((row + dh) << 6) + sw)) << 6) + k0;
                    aH = *(const short8*)&Ah[off];
                    aL = *(const short8*)&Al[off];
                }
#pragma unroll
                for (int o = 0; o < NOUT; ++o)
#pragma unroll
                    for (int cb = 0; cb < 2; ++cb) {
                        int co = chalf + (cb << 4) + l15;
                        size_t woff = (((size_t)tap) << 12) + (((size_t)co) << 6) + k0;
                        short8 bH = *(const short8*)&wh[o][woff];
                        short8 bL = *(const short8*)&wl[o][woff];
                        acc[o][cb] = __builtin_amdgcn_mfma_f32_16x16x32_bf16(
                            aH, bH, acc[o][cb], 0, 0, 0);
                        acc[o][cb] = __builtin_amdgcn_mfma_f32_16x16x32_bf16(
                            aH, bL, acc[o][cb], 0, 0, 0);
                        acc[o][cb] = __builtin_amdgcn_mfma_f32_16x16x32_bf16(
                            aL, bH, acc[o][cb], 0, 0, 0);
                    }
            }
        }
    }

    if (MODE == 0) {
        // write fp32 out + per-block channel stats
        float sc_[2], ss_[2];
#pragma unroll
        for (int cb = 0; cb < 2; ++cb) {
            int co = chalf + (cb << 4) + l15;
            float s = 0.f, ss = 0.f;
#pragma unroll
            for (int r = 0; r < 4; ++r) {
                int pix = (row << 6) + wbase + (quad << 2) + r;
                float v = acc[0][cb][r];
                outF[(((size_t)pix) << 6) + co] = v;
                s += v;
                ss += v * v;
            }
            sc_[cb] = s;
            ss_[cb] = ss;
        }
#pragma unroll
        for (int off = 16; off < 64; off <<= 1) {
#pragma unroll
            for (int cb = 0; cb < 2; ++cb) {
                sc_[cb] += __shfl_xor(sc_[cb], off);
                ss_[cb] += __shfl_xor(ss_[cb], off);
            }
        }
        if (quad == 0) {
#pragma unroll
            for (int cb = 0; cb < 2; ++cb) {
                redS[wv][chalf + (cb << 4) + l15] = sc_[cb];
                redSS[wv][chalf + (cb << 4) + l15] = ss_[cb];
            }
        }
        __syncthreads();
        if (t < 64) {
            int p0 = (t >> 5) & 1;  // which wave pair covers channel t
            float S = redS[p0][t] + redS[p0 + 2][t];
            float SS = redSS[p0][t] + redSS[p0 + 2][t];
            part[blockIdx.x * 64 + t] = S;
            part[32768 + blockIdx.x * 64 + t] = SS;
        }
    } else {
        const int b = row >> 6;
#pragma unroll
        for (int cb = 0; cb < 2; ++cb) {
            int co = chalf + (cb << 4) + l15;
            float bth = b0[co], bph = b1[co], bg = b2[co];
            int pixb = (row << 6) + wbase + (quad << 2);
#pragma unroll
            for (int r = 0; r < 4; ++r) {
                size_t off = (((size_t)(pixb + r)) << 6) + co;
                float v = acc[0][cb][r] + bth;
                ushort hh = f2bf(v);
                o0h[off] = hh;
                o0l[off] = f2bf(v - bf2f(hh));
                v = acc[1][cb][r] + bph;
                hh = f2bf(v);
                o1h[off] = hh;
                o1l[off] = f2bf(v - bf2f(hh));
            }
            int n0 = pixb & 4095;
            ushort4 gv;
            gv.x = f2bf(acc[2][cb][0] + bg);
            gv.y = f2bf(acc[2][cb][1] + bg);
            gv.z = f2bf(acc[2][cb][2] + bg);
            gv.w = f2bf(acc[2][cb][3] + bg);
            *(ushort4*)&o2t[(((size_t)b) << 18) + (((size_t)co) << 12) + n0] = gv;
        }
    }
}

// ---------------------------------------------------------------------------
// statsB: reduce 512 block-partials per channel -> BN scale/shift.
// ---------------------------------------------------------------------------
__global__ __launch_bounds__(256) void statsB_k(
    const float* __restrict__ part, const float* __restrict__ gamma,
    const float* __restrict__ beta, float* __restrict__ scale,
    float* __restrict__ shift)
{
    __shared__ float rs[4][64], rss[4][64];
    const int t = threadIdx.x, c = t & 63, seg = t >> 6;
    float S = 0.f, SS = 0.f;
    for (int k = seg * 128; k < seg * 128 + 128; ++k) {
        S += part[k * 64 + c];
        SS += part[32768 + k * 64 + c];
    }
    rs[seg][c] = S;
    rss[seg][c] = SS;
    __syncthreads();
    if (t < 64) {
        float Sf = rs[0][t] + rs[1][t] + rs[2][t] + rs[3][t];
        float SSf = rss[0][t] + rss[1][t] + rss[2][t] + rss[3][t];
        float mean = Sf * (1.f / 16384.f);
        float var = SSf * (1.f / 16384.f) - mean * mean;
        float sc = gamma[t] * rsqrtf(var + 1e-5f);
        scale[t] = sc;
        shift[t] = beta[t] - mean * sc;
    }
}

// ---------------------------------------------------------------------------
// x1prep: c1T fp32 [pix][ch] -> relu(BN) -> x1T bf16 hi/lo.
// ---------------------------------------------------------------------------
__global__ __launch_bounds__(256) void x1prep_k(
    const float* __restrict__ c1T, const float* __restrict__ sc,
    const float* __restrict__ sh, ushort* __restrict__ xh,
    ushort* __restrict__ xl)
{
    int p = blockIdx.x * 256 + threadIdx.x;  // < 262144
    int c4 = (p & 15) << 2;
    float4 v = *(const float4*)&c1T[(size_t)p << 2];
    float4 s4 = *(const float4*)&sc[c4];
    float4 h4 = *(const float4*)&sh[c4];
    float r0 = fmaxf(v.x * s4.x + h4.x, 0.f);
    float r1 = fmaxf(v.y * s4.y + h4.y, 0.f);
    float r2 = fmaxf(v.z * s4.z + h4.z, 0.f);
    float r3 = fmaxf(v.w * s4.w + h4.w, 0.f);
    ushort4 hi, lo;
    hi.x = f2bf(r0); lo.x = f2bf(r0 - bf2f(hi.x));
    hi.y = f2bf(r1); lo.y = f2bf(r1 - bf2f(hi.y));
    hi.z = f2bf(r2); lo.z = f2bf(r2 - bf2f(hi.z));
    hi.w = f2bf(r3); lo.w = f2bf(r3 - bf2f(hi.w));
    *(ushort4*)&xh[(size_t)p << 2] = hi;
    *(ushort4*)&xl[(size_t)p << 2] = lo;
}

// ---------------------------------------------------------------------------
// Flash attention, split-Q (32-row Q tiles, grid 512 = 2 blocks/CU).
// Q/K/V fragments load DIRECTLY from global ([n][c] hi/lo and g16 [c][n]
// are exactly MFMA A/B layouts) -- no staging LDS. Only P round-trips
// through LDS (double-buffered, 8 KB, XOR-swizzled): 1 barrier/step.
// Static max M=30, hi/lo compensated QK^T (3 MFMAs), l via ones-MFMA.
// ---------------------------------------------------------------------------
__device__ __forceinline__ short8 ldfrag(const ushort* base, int row, int ch) {
    return *(const short8*)&base[(row << 6) + (((ch ^ (row & 7))) << 3)];
}

__global__ __launch_bounds__(256) void attn_k(
    const ushort* __restrict__ thT_hi, const ushort* __restrict__ thT_lo,
    const ushort* __restrict__ phT_hi, const ushort* __restrict__ phT_lo,
    const ushort* __restrict__ g16, ushort* __restrict__ yh,
    ushort* __restrict__ yl)
{
    __shared__ __align__(16) ushort Pt[2][2048];

    const int t = threadIdx.x, lane = t & 63, wv = t >> 6;
    const int quad = lane >> 4, l15 = lane & 15;
    const int b = blockIdx.x >> 7;
    const int q0 = (blockIdx.x & 127) << 5;
    const int qh = (wv >> 1) << 4;   // wave's q offset (0/16)
    const int kvh = (wv & 1) << 5;   // wave's kv half (S) / channel half (PV)

    const size_t cb64 = ((size_t)b) << 18;
    const ushort* Qh_g = thT_hi + cb64;
    const ushort* Ql_g = thT_lo + cb64;
    const ushort* Kh_g = phT_hi + cb64;
    const ushort* Kl_g = phT_lo + cb64;
    const ushort* Vg = g16 + cb64;

    // Q fragments: static across all steps -> hoist
    short8 aHi[2], aLo[2];
#pragma unroll
    for (int ks = 0; ks < 2; ++ks) {
        size_t off = (((size_t)(q0 + qh + l15)) << 6) + ks * 32 + quad * 8;
        aHi[ks] = *(const short8*)&Qh_g[off];
        aLo[ks] = *(const short8*)&Ql_g[off];
    }

    f32x4 oacc[2];
    f32x4 lacc;
#pragma unroll
    for (int j = 0; j < 4; ++j) {
        lacc[j] = 0.f;
        oacc[0][j] = 0.f;
        oacc[1][j] = 0.f;
    }
    short8 onesB;
    {
        short ov = (l15 == 0) ? (short)0x3F80 : (short)0;
#pragma unroll
        for (int j = 0; j < 8; ++j) onesB[j] = ov;
    }

    for (int step = 0; step < 64; ++step) {
        const int m0 = step << 6;
        const int buf = step & 1;

        // K fragments straight from global
        short8 bHi[2][2], bLo[2][2];
#pragma unroll
        for (int cb = 0; cb < 2; ++cb) {
            int kv = m0 + kvh + (cb << 4) + l15;
#pragma unroll
            for (int ks = 0; ks < 2; ++ks) {
                size_t off = (((size_t)kv) << 6) + ks * 32 + quad * 8;
                bHi[cb][ks] = *(const short8*)&Kh_g[off];
                bLo[cb][ks] = *(const short8*)&Kl_g[off];
            }
        }
        f32x4 sacc[2];
#pragma unroll
        for (int j = 0; j < 4; ++j) { sacc[0][j] = 0.f; sacc[1][j] = 0.f; }
#pragma unroll
        for (int ks = 0; ks < 2; ++ks)
#pragma unroll
            for (int cb = 0; cb < 2; ++cb) {
                sacc[cb] = __builtin_amdgcn_mfma_f32_16x16x32_bf16(
                    aHi[ks], bHi[cb][ks], sacc[cb], 0, 0, 0);
                sacc[cb] = __builtin_amdgcn_mfma_f32_16x16x32_bf16(
                    aHi[ks], bLo[cb][ks], sacc[cb], 0, 0, 0);
                sacc[cb] = __builtin_amdgcn_mfma_f32_16x16x32_bf16(
                    aLo[ks], bHi[cb][ks], sacc[cb], 0, 0, 0);
            }

        // exp + P write (C-layout -> swizzled LDS)
#pragma unroll
        for (int cb = 0; cb < 2; ++cb) {
            int pcol = kvh + (cb << 4) + l15;
#pragma unroll
            for (int r = 0; r < 4; ++r) {
                int prow = qh + (quad << 2) + r;
                float p = __expf(sacc[cb][r] - 30.f);
                Pt[buf][(prow << 6) + (((pcol >> 3) ^ (prow & 7)) << 3) +
                        (pcol & 7)] = f2bf(p);
            }
        }
        __syncthreads();

        // P A-frags from LDS; V B-frags straight from global
        short8 pa[2];
#pragma unroll
        for (int ks = 0; ks < 2; ++ks)
            pa[ks] = ldfrag(&Pt[buf][0], qh + l15, ks * 4 + quad);
        short8 vb[2][2];
#pragma unroll
        for (int cb = 0; cb < 2; ++cb) {
            int c = kvh + (cb << 4) + l15;
#pragma unroll
            for (int ks = 0; ks < 2; ++ks)
                vb[cb][ks] = *(const short8*)&Vg[(((size_t)c) << 12) + m0 +
                                                 ks * 32 + quad * 8];
        }
#pragma unroll
        for (int ks = 0; ks < 2; ++ks) {
#pragma unroll
            for (int cb = 0; cb < 2; ++cb)
                oacc[cb] = __builtin_amdgcn_mfma_f32_16x16x32_bf16(
                    pa[ks], vb[cb][ks], oacc[cb], 0, 0, 0);
            lacc = __builtin_amdgcn_mfma_f32_16x16x32_bf16(
                pa[ks], onesB, lacc, 0, 0, 0);
        }
    }

    // epilogue: y = O / l, bf16 hi/lo [b][n][c]
    float linv[4];
#pragma unroll
    for (int r = 0; r < 4; ++r)
        linv[r] = 1.f / __shfl(lacc[r], lane & 48);
#pragma unroll
    for (int cb = 0; cb < 2; ++cb) {
        int cc = kvh + (cb << 4) + l15;
#pragma unroll
        for (int r = 0; r < 4; ++r) {
            int nn = q0 + qh + (quad << 2) + r;
            float v = oacc[cb][r] * linv[r];
            size_t off = cb64 + (((size_t)nn) << 6) + cc;
            ushort hh = f2bf(v);
            yh[off] = hh;
            yl[off] = f2bf(v - bf2f(hh));
        }
    }
}

// ---------------------------------------------------------------------------
// 1x1 conv + bias + residual, MFMA, 32-pix blocks (grid 512).
// ---------------------------------------------------------------------------
__global__ __launch_bounds__(256) void conv1x1_k(
    const ushort* __restrict__ yh, const ushort* __restrict__ yl,
    const ushort* __restrict__ wh, const ushort* __restrict__ wl,
    const float* __restrict__ Wb, const float* __restrict__ x,
    ushort* __restrict__ zh, ushort* __restrict__ zl)
{
    const int t = threadIdx.x, lane = t & 63, wv = t >> 6;
    const int quad = lane >> 4, l15 = lane & 15;
    const int chalf = (wv & 1) << 5;
    const int P0 = blockIdx.x << 5;
    const int pbase = P0 + ((wv >> 1) << 4);

    f32x4 acc[2];
#pragma unroll
    for (int j = 0; j < 4; ++j) { acc[0][j] = 0.f; acc[1][j] = 0.f; }

#pragma unroll
    for (int kc = 0; kc < 2; ++kc) {
        const int k0 = kc * 32 + quad * 8;
        size_t aoff = (((size_t)(pbase + l15)) << 6) + k0;
        short8 aH = *(const short8*)&yh[aoff];
        short8 aL = *(const short8*)&yl[aoff];
#pragma unroll
        for (int cb = 0; cb < 2; ++cb) {
            int co = chalf + (cb << 4) + l15;
            short8 bH = *(const short8*)&wh[(((size_t)co) << 6) + k0];
            short8 bL = *(const short8*)&wl[(((size_t)co) << 6) + k0];
            acc[cb] = __builtin_amdgcn_mfma_f32_16x16x32_bf16(aH, bH, acc[cb], 0, 0, 0);
            acc[cb] = __builtin_amdgcn_mfma_f32_16x16x32_bf16(aH, bL, acc[cb], 0, 0, 0);
            acc[cb] = __builtin_amdgcn_mfma_f32_16x16x32_bf16(aL, bH, acc[cb], 0, 0, 0);
        }
    }

    const int b = P0 >> 12;
    const int pixb = pbase + (quad << 2);
    const int n0 = pixb & 4095;
#pragma unroll
    for (int cb = 0; cb < 2; ++cb) {
        int co = chalf + (cb << 4) + l15;
        float bias = Wb[co];
        float4 xr = *(const float4*)&x[(((size_t)(b * 64 + co)) << 12) + n0];
        float xa[4] = {xr.x, xr.y, xr.z, xr.w};
#pragma unroll
        for (int r = 0; r < 4; ++r) {
            float v = acc[cb][r] + bias + xa[r];
            size_t off = (((size_t)(pixb + r)) << 6) + co;
            ushort hh = f2bf(v);
            zh[off] = hh;
            zl[off] = f2bf(v - bf2f(hh));
        }
    }
}

// ---------------------------------------------------------------------------
// Final: BN2 apply + relu + transpose back to [B][C][H][W].
// ---------------------------------------------------------------------------
__global__ __launch_bounds__(256) void bnreluT_k(
    const float* __restrict__ c2T, const float* __restrict__ sc,
    const float* __restrict__ sh, float* __restrict__ out)
{
    __shared__ __align__(16) float T[64 * 68];
    const int b = blockIdx.x >> 6, n0 = (blockIdx.x & 63) << 6, t = threadIdx.x;
    for (int p = t; p < 1024; p += 256) {
        int n = p >> 4, c4 = (p & 15) << 2;
        float4 v = *(const float4*)&c2T[(((size_t)(b * 4096 + n0 + n)) << 6) + c4];
        float4 s4 = *(const float4*)&sc[c4];
        float4 h4 = *(const float4*)&sh[c4];
        T[(c4 + 0) * 68 + n] = fmaxf(v.x * s4.x + h4.x, 0.f);
        T[(c4 + 1) * 68 + n] = fmaxf(v.y * s4.y + h4.y, 0.f);
        T[(c4 + 2) * 68 + n] = fmaxf(v.z * s4.z + h4.z, 0.f);
        T[(c4 + 3) * 68 + n] = fmaxf(v.w * s4.w + h4.w, 0.f);
    }
    __syncthreads();
    for (int p = t; p < 1024; p += 256) {
        int c = p >> 4, n4 = (p & 15) << 2;
        float4 r;
        r.x = T[c * 68 + n4 + 0];
        r.y = T[c * 68 + n4 + 1];
        r.z = T[c * 68 + n4 + 2];
        r.w = T[c * 68 + n4 + 3];
        *(float4*)&out[(((size_t)(b * 64 + c)) << 12) + n0 + n4] = r;
    }
}

// ---------------------------------------------------------------------------
extern "C" void kernel_launch(void* const* d_in, const int* in_sizes, int n_in,
                              void* d_out, int out_size, void* d_ws,
                              size_t ws_size, hipStream_t stream)
{
    const float* x    = (const float*)d_in[0];
    const float* c1w  = (const float*)d_in[1];
    const float* bn1g = (const float*)d_in[2];
    const float* bn1b = (const float*)d_in[3];
    const float* thw  = (const float*)d_in[4];
    const float* thb  = (const float*)d_in[5];
    const float* phw  = (const float*)d_in[6];
    const float* phb  = (const float*)d_in[7];
    const float* gw   = (const float*)d_in[8];
    const float* gb   = (const float*)d_in[9];
    const float* Wwt  = (const float*)d_in[10];
    const float* Wbs  = (const float*)d_in[11];
    const float* c2w  = (const float*)d_in[12];
    const float* bn2g = (const float*)d_in[13];
    const float* bn2b = (const float*)d_in[14];
    float* out = (float*)d_out;

    float* ws = (float*)d_ws;
    ushort* xT_hi = (ushort*)ws;             // region A
    ushort* xT_lo = xT_hi + (1 << 20);
    ushort* x1T_hi = xT_hi;                  // xT dead after conv1
    ushort* x1T_lo = xT_lo;
    ushort* zT_hi = xT_hi;                   // x1T dead after fused conv
    ushort* zT_lo = xT_lo;
    float* c1T = ws + (1 << 20);             // region B
    ushort* yT_hi = (ushort*)c1T;            // c1T dead after x1prep
    ushort* yT_lo = yT_hi + (1 << 20);
    ushort* thT_hi = (ushort*)(ws + (2 << 20));  // region C
    ushort* thT_lo = thT_hi + (1 << 20);
    ushort* phT_hi = (ushort*)(ws + (3 << 20));  // region D
    ushort* phT_lo = phT_hi + (1 << 20);
    ushort* g16 = (ushort*)(ws + (4 << 20));     // region E
    float* c2T = ws + (2 << 20);             // thT dead after attn
    ushort* wp = (ushort*)(ws + (9 << 19));  // weights at 4.5M
    float* part = ws + (5 << 20) - 65536;
    float* stats = ws + (5 << 20);
    float* sc1 = stats, *sh1 = stats + 64, *sc2 = stats + 128, *sh2 = stats + 192;

    ushort* wc1h = wp;                ushort* wc1l = wc1h + 36864;
    ushort* wthh = wp + 1 * 73728;    ushort* wthl = wthh + 36864;
    ushort* wphh = wp + 2 * 73728;    ushort* wphl = wphh + 36864;
    ushort* wgh  = wp + 3 * 73728;    ushort* wgl  = wgh + 36864;
    ushort* wc2h = wp + 4 * 73728;    ushort* wc2l = wc2h + 36864;
    ushort* w11h = wp + 5 * 73728;    ushort* w11l = w11h + 4096;

    prep_all_k<<<992, 256, 0, stream>>>(x, xT_hi, xT_lo, c1w, thw, phw, gw,
                                        c2w, Wwt, wp);
    conv_mfma_k<1, 0><<<512, 256, 0, stream>>>(
        xT_hi, xT_lo, wc1h, wc1l, nullptr, nullptr, nullptr, nullptr,
        nullptr, nullptr, nullptr, c1T, part, nullptr, nullptr, nullptr,
        nullptr, nullptr);
    statsB_k<<<1, 256, 0, stream>>>(part, bn1g, bn1b, sc1, sh1);
    x1prep_k<<<1024, 256, 0, stream>>>(c1T, sc1, sh1, x1T_hi, x1T_lo);
    conv_mfma_k<3, 1><<<512, 256, 0, stream>>>(
        x1T_hi, x1T_lo, wthh, wthl, wphh, wphl, wgh, wgl, thb, phb, gb,
        nullptr, nullptr, thT_hi, thT_lo, phT_hi, phT_lo, g16);
    attn_k<<<512, 256, 0, stream>>>(thT_hi, thT_lo, phT_hi, phT_lo, g16,
                                    yT_hi, yT_lo);
    conv1x1_k<<<512, 256, 0, stream>>>(yT_hi, yT_lo, w11h, w11l, Wbs, x,
                                       zT_hi, zT_lo);
    conv_mfma_k<1, 0><<<512, 256, 0, stream>>>(
        zT_hi, zT_lo, wc2h, wc2l, nullptr, nullptr, nullptr, nullptr,
        nullptr, nullptr, nullptr, c2T, part, nullptr, nullptr, nullptr,
        nullptr, nullptr);
    statsB_k<<<1, 256, 0, stream>>>(part, bn2g, bn2b, sc2, sh2);
    bnreluT_k<<<256, 256, 0, stream>>>(c2T, sc2, sh2, out);
}

// Round 5
// 297.236 us; speedup vs baseline: 1.4050x; 1.4050x over previous
//
#include <hip/hip_runtime.h>
#include <math.h>

// B=4, C=64, H=W=64, N=4096, NPIX=16384. All fp32 in/out.
// Pixel-major [pix][ch] bf16 hi/lo pipeline. ws (floats), footprint 5M+256:
//  A ws+0..1M   : xT hi/lo -> x1T hi/lo -> O0 (attn partial, fp32) -> zT hi/lo
//  B ws+1M..2M  : c1T fp32 -> O1 (attn partial, fp32) -> c2T fp32
//  C ws+2M..3M  : thT hi/lo -> yT hi/lo
//  D ws+3M..4M  : phT hi/lo
//  E ws+4M..4.5M: g16 (bf16 [B][C][N])
//  wp ws+4.5M   : prepped weights ; part ws+5M-65536 ; stats ws+5M

typedef __attribute__((ext_vector_type(8))) short short8;
typedef __attribute__((ext_vector_type(4))) float f32x4;

__device__ __forceinline__ ushort f2bf(float x) {
    unsigned u = __float_as_uint(x);
    unsigned r = (u + 0x7FFFu + ((u >> 16) & 1u)) >> 16;  // RNE
    return (ushort)r;
}
__device__ __forceinline__ float bf2f(ushort h) {
    return __uint_as_float(((unsigned)h) << 16);
}

// ---------------------------------------------------------------------------
// prep_all: blocks <256: x -> xT [pix][ch] bf16 hi/lo. blocks >=256: weights.
// ---------------------------------------------------------------------------
__global__ __launch_bounds__(256) void prep_all_k(
    const float* __restrict__ x, ushort* __restrict__ xh,
    ushort* __restrict__ xl,
    const float* __restrict__ w0, const float* __restrict__ w1,
    const float* __restrict__ w2, const float* __restrict__ w3,
    const float* __restrict__ w4, const float* __restrict__ w5,
    ushort* __restrict__ wbase)
{
    __shared__ __align__(16) float T[64 * 68];
    const int blk = blockIdx.x, t = threadIdx.x;
    if (blk < 256) {
        const int b = blk >> 6, n0 = (blk & 63) << 6;
        for (int p = t; p < 1024; p += 256) {
            int c = p >> 4, n4 = (p & 15) << 2;
            *(float4*)&T[c * 68 + n4] =
                *(const float4*)&x[(((size_t)(b * 64 + c)) << 12) + n0 + n4];
        }
        __syncthreads();
        for (int p = t; p < 1024; p += 256) {
            int n = p >> 4, c4 = (p & 15) << 2;
            size_t off = (((size_t)(b * 4096 + n0 + n)) << 6) + c4;
            ushort4 hi, lo;
            float v;
            v = T[(c4 + 0) * 68 + n]; hi.x = f2bf(v); lo.x = f2bf(v - bf2f(hi.x));
            v = T[(c4 + 1) * 68 + n]; hi.y = f2bf(v); lo.y = f2bf(v - bf2f(hi.y));
            v = T[(c4 + 2) * 68 + n]; hi.z = f2bf(v); lo.z = f2bf(v - bf2f(hi.z));
            v = T[(c4 + 3) * 68 + n]; hi.w = f2bf(v); lo.w = f2bf(v - bf2f(hi.w));
            *(ushort4*)&xh[off] = hi;
            *(ushort4*)&xl[off] = lo;
        }
    } else {
        const float* W[6] = {w0, w1, w2, w3, w4, w5};
        int q = blk - 256;
        if (q < 720) {
            int s = q / 144, bi = q - s * 144;
            int idx = bi * 256 + t;
            if (idx >= 36864) return;
            int co = idx / 576;
            int r = idx - co * 576;
            int ci = r / 9;
            int tap = r - ci * 9;
            float v = W[s][idx];
            ushort* hi = wbase + (size_t)s * 73728;
            ushort* lo = hi + 36864;
            int off = tap * 4096 + co * 64 + ci;
            ushort h = f2bf(v);
            hi[off] = h;
            lo[off] = f2bf(v - bf2f(h));
        } else {
            int idx = (q - 720) * 256 + t;
            if (idx >= 4096) return;
            float v = W[5][idx];
            ushort* hi = wbase + 5 * 73728;
            ushort* lo = hi + 4096;
            ushort h = f2bf(v);
            hi[idx] = h;
            lo[idx] = f2bf(v - bf2f(h));
        }
    }
}

// ---------------------------------------------------------------------------
// MFMA 3x3 conv, 9 shifted GEMM taps. Block = 64 pix (one h-row) x 32 co.
// Grid 512 (2 blk/CU). Waves: (wv>>1) = pixel half (32), (wv&1) = co quarter
// (16). Wave tile 32pix x 16co: B-traffic per wave identical to the proven
// r3 shape (32x32 tile), A-traffic 2x but L2-hot. hi/lo compensated.
// MODE 0: fp32 out + fused BN partial stats. MODE 1: theta/phi hi/lo, g16.
// ---------------------------------------------------------------------------
template <int NOUT, int MODE>
__global__ __launch_bounds__(256) void conv_mfma_k(
    const ushort* __restrict__ Ah, const ushort* __restrict__ Al,
    const ushort* __restrict__ w0h, const ushort* __restrict__ w0l,
    const ushort* __restrict__ w1h, const ushort* __restrict__ w1l,
    const ushort* __restrict__ w2h, const ushort* __restrict__ w2l,
    const float* __restrict__ b0, const float* __restrict__ b1,
    const float* __restrict__ b2,
    float* __restrict__ outF, float* __restrict__ part,
    ushort* __restrict__ o0h, ushort* __restrict__ o0l,
    ushort* __restrict__ o1h, ushort* __restrict__ o1l,
    ushort* __restrict__ o2t)
{
    __shared__ float redS[4][16], redSS[4][16];
    const int t = threadIdx.x, lane = t & 63, wv = t >> 6;
    const int quad = lane >> 4, l15 = lane & 15;
    const int bx = blockIdx.x;
    const int row = bx >> 1;        // b*64 + h
    const int h = row & 63;
    const int co0 = (bx & 1) << 5;
    const int wbase = (wv >> 1) << 5;
    const int coq = (wv & 1) << 4;
    const int co = co0 + coq + l15;

    const ushort* wh[3] = {w0h, w1h, w2h};
    const ushort* wl[3] = {w0l, w1l, w2l};

    f32x4 acc[NOUT][2];
#pragma unroll
    for (int o = 0; o < NOUT; ++o)
#pragma unroll
        for (int rb = 0; rb < 2; ++rb)
#pragma unroll
            for (int j = 0; j < 4; ++j) acc[o][rb][j] = 0.f;

#pragma unroll
    for (int dh = -1; dh <= 1; ++dh) {
        if ((unsigned)(h + dh) >= 64u) continue;  // block-uniform
#pragma unroll
        for (int dw = -1; dw <= 1; ++dw) {
            const int tap = (dh + 1) * 3 + (dw + 1);
#pragma unroll
            for (int kc = 0; kc < 2; ++kc) {
                const int k0 = kc * 32 + quad * 8;
                short8 aH[2], aL[2];
#pragma unroll
                for (int rb = 0; rb < 2; ++rb) {
                    const int sw = wbase + (rb << 4) + l15 + dw;
                    short8 z = {0, 0, 0, 0, 0, 0, 0, 0};
                    aH[rb] = z;
                    aL[rb] = z;
                    if ((unsigned)sw < 64u) {
                        size_t off = (((size_t)(((row + dh) << 6) + sw)) << 6) + k0;
                        aH[rb] = *(const short8*)&Ah[off];
                        aL[rb] = *(const short8*)&Al[off];
                    }
                }
#pragma unroll
                for (int o = 0; o < NOUT; ++o) {
                    size_t woff = (((size_t)tap) << 12) + (((size_t)co) << 6) + k0;
                    short8 bH = *(const short8*)&wh[o][woff];
                    short8 bL = *(const short8*)&wl[o][woff];
#pragma unroll
                    for (int rb = 0; rb < 2; ++rb) {
                        acc[o][rb] = __builtin_amdgcn_mfma_f32_16x16x32_bf16(
                            aH[rb], bH, acc[o][rb], 0, 0, 0);
                        acc[o][rb] = __builtin_amdgcn_mfma_f32_16x16x32_bf16(
                            aH[rb], bL, acc[o][rb], 0, 0, 0);
                        acc[o][rb] = __builtin_amdgcn_mfma_f32_16x16x32_bf16(
                            aL[rb], bH, acc[o][rb], 0, 0, 0);
                    }
                }
            }
        }
    }

    if (MODE == 0) {
        float s = 0.f, ss = 0.f;
#pragma unroll
        for (int rb = 0; rb < 2; ++rb) {
#pragma unroll
            for (int r = 0; r < 4; ++r) {
                int pix = (row << 6) + wbase + (rb << 4) + (quad << 2) + r;
                float v = acc[0][rb][r];
                outF[(((size_t)pix) << 6) + co] = v;
                s += v;
                ss += v * v;
            }
        }
#pragma unroll
        for (int off = 16; off < 64; off <<= 1) {
            s += __shfl_xor(s, off);
            ss += __shfl_xor(ss, off);
        }
        if (quad == 0) {
            redS[wv][l15] = s;
            redSS[wv][l15] = ss;
        }
        __syncthreads();
        if (t < 32) {
            int cq = t >> 4, lc = t & 15;
            float S = redS[cq][lc] + redS[2 + cq][lc];
            float SS = redSS[cq][lc] + redSS[2 + cq][lc];
            part[bx * 32 + t] = S;
            part[32768 + bx * 32 + t] = SS;
        }
    } else {
        const int b = row >> 6;
        float bth = b0[co], bph = b1[co], bg = b2[co];
#pragma unroll
        for (int rb = 0; rb < 2; ++rb) {
            int pixb = (row << 6) + wbase + (rb << 4) + (quad << 2);
#pragma unroll
            for (int r = 0; r < 4; ++r) {
                size_t off = (((size_t)(pixb + r)) << 6) + co;
                float v = acc[0][rb][r] + bth;
                ushort hh = f2bf(v);
                o0h[off] = hh;
                o0l[off] = f2bf(v - bf2f(hh));
                v = acc[1][rb][r] + bph;
                hh = f2bf(v);
                o1h[off] = hh;
                o1l[off] = f2bf(v - bf2f(hh));
            }
            int n0 = pixb & 4095;
            ushort4 gv;
            gv.x = f2bf(acc[2][rb][0] + bg);
            gv.y = f2bf(acc[2][rb][1] + bg);
            gv.z = f2bf(acc[2][rb][2] + bg);
            gv.w = f2bf(acc[2][rb][3] + bg);
            *(ushort4*)&o2t[(((size_t)b) << 18) + (((size_t)co) << 12) + n0] = gv;
        }
    }
}

// ---------------------------------------------------------------------------
// statsB: reduce per-block partials -> BN scale/shift. part[bx*32+c32],
// bx = row*2 + (ch>>5).
// ---------------------------------------------------------------------------
__global__ __launch_bounds__(256) void statsB_k(
    const float* __restrict__ part, const float* __restrict__ gamma,
    const float* __restrict__ beta, float* __restrict__ scale,
    float* __restrict__ shift)
{
    __shared__ float rs[4][64], rss[4][64];
    const int t = threadIdx.x, c = t & 63, seg = t >> 6;
    const int cohalf = c >> 5, c32 = c & 31;
    float S = 0.f, SS = 0.f;
    for (int k = seg * 64; k < seg * 64 + 64; ++k) {
        int bxx = k * 2 + cohalf;
        S += part[bxx * 32 + c32];
        SS += part[32768 + bxx * 32 + c32];
    }
    rs[seg][c] = S;
    rss[seg][c] = SS;
    __syncthreads();
    if (t < 64) {
        float Sf = rs[0][t] + rs[1][t] + rs[2][t] + rs[3][t];
        float SSf = rss[0][t] + rss[1][t] + rss[2][t] + rss[3][t];
        float mean = Sf * (1.f / 16384.f);
        float var = SSf * (1.f / 16384.f) - mean * mean;
        float sc = gamma[t] * rsqrtf(var + 1e-5f);
        scale[t] = sc;
        shift[t] = beta[t] - mean * sc;
    }
}

// ---------------------------------------------------------------------------
// x1prep: c1T fp32 [pix][ch] -> relu(BN) -> x1T bf16 hi/lo.
// ---------------------------------------------------------------------------
__global__ __launch_bounds__(256) void x1prep_k(
    const float* __restrict__ c1T, const float* __restrict__ sc,
    const float* __restrict__ sh, ushort* __restrict__ xh,
    ushort* __restrict__ xl)
{
    int p = blockIdx.x * 256 + threadIdx.x;  // < 262144
    int c4 = (p & 15) << 2;
    float4 v = *(const float4*)&c1T[(size_t)p << 2];
    float4 s4 = *(const float4*)&sc[c4];
    float4 h4 = *(const float4*)&sh[c4];
    float r0 = fmaxf(v.x * s4.x + h4.x, 0.f);
    float r1 = fmaxf(v.y * s4.y + h4.y, 0.f);
    float r2 = fmaxf(v.z * s4.z + h4.z, 0.f);
    float r3 = fmaxf(v.w * s4.w + h4.w, 0.f);
    ushort4 hi, lo;
    hi.x = f2bf(r0); lo.x = f2bf(r0 - bf2f(hi.x));
    hi.y = f2bf(r1); lo.y = f2bf(r1 - bf2f(hi.y));
    hi.z = f2bf(r2); lo.z = f2bf(r2 - bf2f(hi.z));
    hi.w = f2bf(r3); lo.w = f2bf(r3 - bf2f(hi.w));
    *(ushort4*)&xh[(size_t)p << 2] = hi;
    *(ushort4*)&xl[(size_t)p << 2] = lo;
}

// ---------------------------------------------------------------------------
// Flash attention, r3 structure (LDS staging + register prefetch) + 2-way
// KV split (static max M=30 makes softmax associative: partial O and l sum
// exactly). Grid 512 = 2 blk/CU. XCD swizzle: blockIdx&7 -> (batch, half),
// so each XCD's K/V working set (~0.8 MB) is L2-resident.
// Writes partial O fp32 [b][n][c] and partial l; reduce_k combines.
// ---------------------------------------------------------------------------
__device__ __forceinline__ short8 ldfrag(const ushort* base, int row, int ch) {
    return *(const short8*)&base[(row << 6) + (((ch ^ (row & 7))) << 3)];
}

__global__ __launch_bounds__(256) void attn_k(
    const ushort* __restrict__ thT_hi, const ushort* __restrict__ thT_lo,
    const ushort* __restrict__ phT_hi, const ushort* __restrict__ phT_lo,
    const ushort* __restrict__ g16, float* __restrict__ O0,
    float* __restrict__ O1, float* __restrict__ lp)
{
    __shared__ __align__(16) ushort Qhi[4096], Qlo[4096], Khi[4096], Klo[4096];
    __shared__ __align__(16) ushort Vt[2][4096];
    __shared__ __align__(16) ushort Pt[4096];

    const int t = threadIdx.x;
    const int bx = blockIdx.x;
    const int xslot = bx & 7;
    const int b = xslot & 3;
    const int half = xslot >> 2;
    const int q0 = (bx >> 3) << 6;
    const int mbase = half << 11;
    const int lane = t & 63;
    const int wv = t >> 6;
    const int quad = lane >> 4;
    const int l15 = lane & 15;
    const int rhalf = (wv >> 1) << 5;
    const int chalf = (wv & 1) << 5;

    const size_t cb64 = ((size_t)b) << 18;
    const ushort* Qh_g = thT_hi + cb64 + (((size_t)q0) << 6);
    const ushort* Ql_g = thT_lo + cb64 + (((size_t)q0) << 6);
    const ushort* Kh_g = phT_hi + cb64;
    const ushort* Kl_g = phT_lo + cb64;
    const ushort* Vg = g16 + cb64;
    float* Op = half ? O1 : O0;
    float* lpd = lp + (half << 14);

#pragma unroll
    for (int rd = 0; rd < 2; ++rd) {
        int ii = rd * 256 + t;
        int row = ii >> 3, ch = ii & 7;
        int off = (row << 6) + ((ch ^ (row & 7)) << 3);
        *(short8*)&Qhi[off] = *(const short8*)&Qh_g[ii << 3];
        *(short8*)&Qlo[off] = *(const short8*)&Ql_g[ii << 3];
        *(short8*)&Khi[off] = *(const short8*)&Kh_g[((mbase + row) << 6) + (ch << 3)];
        *(short8*)&Klo[off] = *(const short8*)&Kl_g[((mbase + row) << 6) + (ch << 3)];
        *(short8*)&Vt[0][off] = *(const short8*)&Vg[(row << 12) + mbase + (ch << 3)];
    }

    f32x4 oacc[2][2];
    f32x4 lacc[2];
#pragma unroll
    for (int rb = 0; rb < 2; ++rb) {
#pragma unroll
        for (int j = 0; j < 4; ++j) lacc[rb][j] = 0.f;
#pragma unroll
        for (int cb = 0; cb < 2; ++cb)
#pragma unroll
            for (int j = 0; j < 4; ++j) oacc[rb][cb][j] = 0.f;
    }
    short8 onesB;
    {
        short ov = (l15 == 0) ? (short)0x3F80 : (short)0;
#pragma unroll
        for (int j = 0; j < 8; ++j) onesB[j] = ov;
    }

    for (int step = 0; step < 32; ++step) {
        const int buf = step & 1;
        __syncthreads();  // K/V(step) visible; P(step-1) consumers done

        short8 rKh[2], rKl[2], rV[2];
        if (step < 31) {
            const int m1 = mbase + ((step + 1) << 6);
#pragma unroll
            for (int rd = 0; rd < 2; ++rd) {
                int ii = rd * 256 + t;
                int row = ii >> 3, ch = ii & 7;
                rKh[rd] = *(const short8*)&Kh_g[((m1 + row) << 6) + (ch << 3)];
                rKl[rd] = *(const short8*)&Kl_g[((m1 + row) << 6) + (ch << 3)];
                rV[rd] = *(const short8*)&Vg[(row << 12) + m1 + (ch << 3)];
            }
        }

        short8 aHi[2][2], aLo[2][2], bHi[2][2], bLo[2][2];
#pragma unroll
        for (int rb = 0; rb < 2; ++rb) {
            int row = rhalf + (rb << 4) + l15;
#pragma unroll
            for (int ks = 0; ks < 2; ++ks) {
                aHi[rb][ks] = ldfrag(Qhi, row, (ks << 2) + quad);
                aLo[rb][ks] = ldfrag(Qlo, row, (ks << 2) + quad);
            }
        }
#pragma unroll
        for (int cb = 0; cb < 2; ++cb) {
            int row = chalf + (cb << 4) + l15;
#pragma unroll
            for (int ks = 0; ks < 2; ++ks) {
                bHi[cb][ks] = ldfrag(Khi, row, (ks << 2) + quad);
                bLo[cb][ks] = ldfrag(Klo, row, (ks << 2) + quad);
            }
        }
        f32x4 sacc[2][2];
#pragma unroll
        for (int rb = 0; rb < 2; ++rb)
#pragma unroll
            for (int cb = 0; cb < 2; ++cb)
#pragma unroll
                for (int j = 0; j < 4; ++j) sacc[rb][cb][j] = 0.f;
#pragma unroll
        for (int ks = 0; ks < 2; ++ks)
#pragma unroll
            for (int rb = 0; rb < 2; ++rb)
#pragma unroll
                for (int cb = 0; cb < 2; ++cb) {
                    sacc[rb][cb] = __builtin_amdgcn_mfma_f32_16x16x32_bf16(
                        aHi[rb][ks], bHi[cb][ks], sacc[rb][cb], 0, 0, 0);
                    sacc[rb][cb] = __builtin_amdgcn_mfma_f32_16x16x32_bf16(
                        aHi[rb][ks], bLo[cb][ks], sacc[rb][cb], 0, 0, 0);
                    sacc[rb][cb] = __builtin_amdgcn_mfma_f32_16x16x32_bf16(
                        aLo[rb][ks], bHi[cb][ks], sacc[rb][cb], 0, 0, 0);
                }
#pragma unroll
        for (int rb = 0; rb < 2; ++rb)
#pragma unroll
            for (int cb = 0; cb < 2; ++cb) {
                int pcol = chalf + (cb << 4) + l15;
#pragma unroll
                for (int r = 0; r < 4; ++r) {
                    int prow = rhalf + (rb << 4) + (quad << 2) + r;
                    float p = __expf(sacc[rb][cb][r] - 30.f);
                    Pt[(prow << 6) + (((pcol >> 3) ^ (prow & 7)) << 3) +
                       (pcol & 7)] = f2bf(p);
                }
            }
        __syncthreads();  // P visible; all S-phase K reads done

        short8 pa[2][2], vb[2][2];
#pragma unroll
        for (int rb = 0; rb < 2; ++rb) {
            int row = rhalf + (rb << 4) + l15;
#pragma unroll
            for (int ks = 0; ks < 2; ++ks)
                pa[rb][ks] = ldfrag(Pt, row, (ks << 2) + quad);
        }
#pragma unroll
        for (int cb = 0; cb < 2; ++cb) {
            int row = chalf + (cb << 4) + l15;
#pragma unroll
            for (int ks = 0; ks < 2; ++ks)
                vb[cb][ks] = ldfrag(&Vt[buf][0], row, (ks << 2) + quad);
        }
#pragma unroll
        for (int ks = 0; ks < 2; ++ks)
#pragma unroll
            for (int rb = 0; rb < 2; ++rb)
#pragma unroll
                for (int cb = 0; cb < 2; ++cb)
                    oacc[rb][cb] = __builtin_amdgcn_mfma_f32_16x16x32_bf16(
                        pa[rb][ks], vb[cb][ks], oacc[rb][cb], 0, 0, 0);
#pragma unroll
        for (int rb = 0; rb < 2; ++rb)
#pragma unroll
            for (int ks = 0; ks < 2; ++ks)
                lacc[rb] = __builtin_amdgcn_mfma_f32_16x16x32_bf16(
                    pa[rb][ks], onesB, lacc[rb], 0, 0, 0);

        if (step < 31) {
#pragma unroll
            for (int rd = 0; rd < 2; ++rd) {
                int ii = rd * 256 + t;
                int row = ii >> 3, ch = ii & 7;
                int off = (row << 6) + ((ch ^ (row & 7)) << 3);
                *(short8*)&Khi[off] = rKh[rd];
                *(short8*)&Klo[off] = rKl[rd];
                *(short8*)&Vt[buf ^ 1][off] = rV[rd];
            }
        }
    }

    // epilogue: write partial l (col-0 lanes) and partial O (no division)
#pragma unroll
    for (int rb = 0; rb < 2; ++rb) {
        if ((wv & 1) == 0 && l15 == 0) {
#pragma unroll
            for (int r = 0; r < 4; ++r) {
                int nn = q0 + rhalf + (rb << 4) + (quad << 2) + r;
                lpd[(b << 12) + nn] = lacc[rb][r];
            }
        }
#pragma unroll
        for (int cb = 0; cb < 2; ++cb) {
            int cc = chalf + (cb << 4) + l15;
#pragma unroll
            for (int r = 0; r < 4; ++r) {
                int nn = q0 + rhalf + (rb << 4) + (quad << 2) + r;
                Op[cb64 + (((size_t)nn) << 6) + cc] = oacc[rb][cb][r];
            }
        }
    }
}

// ---------------------------------------------------------------------------
// reduce: y = (O0+O1)/(l0+l1) -> yT bf16 hi/lo [pix][ch].
// ---------------------------------------------------------------------------
__global__ __launch_bounds__(256) void reduce_k(
    const float* __restrict__ O0, const float* __restrict__ O1,
    const float* __restrict__ lp, ushort* __restrict__ yh,
    ushort* __restrict__ yl)
{
    int p = blockIdx.x * 256 + threadIdx.x;  // < 262144
    int pix = p >> 4;
    float inv = 1.f / (lp[pix] + lp[16384 + pix]);
    float4 a = *(const float4*)&O0[(size_t)p << 2];
    float4 b4 = *(const float4*)&O1[(size_t)p << 2];
    float v0 = (a.x + b4.x) * inv, v1 = (a.y + b4.y) * inv;
    float v2 = (a.z + b4.z) * inv, v3 = (a.w + b4.w) * inv;
    ushort4 hi, lo;
    hi.x = f2bf(v0); lo.x = f2bf(v0 - bf2f(hi.x));
    hi.y = f2bf(v1); lo.y = f2bf(v1 - bf2f(hi.y));
    hi.z = f2bf(v2); lo.z = f2bf(v2 - bf2f(hi.z));
    hi.w = f2bf(v3); lo.w = f2bf(v3 - bf2f(hi.w));
    *(ushort4*)&yh[(size_t)p << 2] = hi;
    *(ushort4*)&yl[(size_t)p << 2] = lo;
}

// ---------------------------------------------------------------------------
// 1x1 conv + bias + residual, MFMA, 32-pix blocks (grid 512).
// ---------------------------------------------------------------------------
__global__ __launch_bounds__(256) void conv1x1_k(
    const ushort* __restrict__ yh, const ushort* __restrict__ yl,
    const ushort* __restrict__ wh, const ushort* __restrict__ wl,
    const float* __restrict__ Wb, const float* __restrict__ x,
    ushort* __restrict__ zh, ushort* __restrict__ zl)
{
    const int t = threadIdx.x, lane = t & 63, wv = t >> 6;
    const int quad = lane >> 4, l15 = lane & 15;
    const int chalf = (wv & 1) << 5;
    const int P0 = blockIdx.x << 5;
    const int pbase = P0 + ((wv >> 1) << 4);

    f32x4 acc[2];
#pragma unroll
    for (int j = 0; j < 4; ++j) { acc[0][j] = 0.f; acc[1][j] = 0.f; }

#pragma unroll
    for (int kc = 0; kc < 2; ++kc) {
        const int k0 = kc * 32 + quad * 8;
        size_t aoff = (((size_t)(pbase + l15)) << 6) + k0;
        short8 aH = *(const short8*)&yh[aoff];
        short8 aL = *(const short8*)&yl[aoff];
#pragma unroll
        for (int cb = 0; cb < 2; ++cb) {
            int co = chalf + (cb << 4) + l15;
            short8 bH = *(const short8*)&wh[(((size_t)co) << 6) + k0];
            short8 bL = *(const short8*)&wl[(((size_t)co) << 6) + k0];
            acc[cb] = __builtin_amdgcn_mfma_f32_16x16x32_bf16(aH, bH, acc[cb], 0, 0, 0);
            acc[cb] = __builtin_amdgcn_mfma_f32_16x16x32_bf16(aH, bL, acc[cb], 0, 0, 0);
            acc[cb] = __builtin_amdgcn_mfma_f32_16x16x32_bf16(aL, bH, acc[cb], 0, 0, 0);
        }
    }

    const int b = P0 >> 12;
    const int pixb = pbase + (quad << 2);
    const int n0 = pixb & 4095;
#pragma unroll
    for (int cb = 0; cb < 2; ++cb) {
        int co = chalf + (cb << 4) + l15;
        float bias = Wb[co];
        float4 xr = *(const float4*)&x[(((size_t)(b * 64 + co)) << 12) + n0];
        float xa[4] = {xr.x, xr.y, xr.z, xr.w};
#pragma unroll
        for (int r = 0; r < 4; ++r) {
            float v = acc[cb][r] + bias + xa[r];
            size_t off = (((size_t)(pixb + r)) << 6) + co;
            ushort hh = f2bf(v);
            zh[off] = hh;
            zl[off] = f2bf(v - bf2f(hh));
        }
    }
}

// ---------------------------------------------------------------------------
// Final: BN2 apply + relu + transpose back to [B][C][H][W].
// ---------------------------------------------------------------------------
__global__ __launch_bounds__(256) void bnreluT_k(
    const float* __restrict__ c2T, const float* __restrict__ sc,
    const float* __restrict__ sh, float* __restrict__ out)
{
    __shared__ __align__(16) float T[64 * 68];
    const int b = blockIdx.x >> 6, n0 = (blockIdx.x & 63) << 6, t = threadIdx.x;
    for (int p = t; p < 1024; p += 256) {
        int n = p >> 4, c4 = (p & 15) << 2;
        float4 v = *(const float4*)&c2T[(((size_t)(b * 4096 + n0 + n)) << 6) + c4];
        float4 s4 = *(const float4*)&sc[c4];
        float4 h4 = *(const float4*)&sh[c4];
        T[(c4 + 0) * 68 + n] = fmaxf(v.x * s4.x + h4.x, 0.f);
        T[(c4 + 1) * 68 + n] = fmaxf(v.y * s4.y + h4.y, 0.f);
        T[(c4 + 2) * 68 + n] = fmaxf(v.z * s4.z + h4.z, 0.f);
        T[(c4 + 3) * 68 + n] = fmaxf(v.w * s4.w + h4.w, 0.f);
    }
    __syncthreads();
    for (int p = t; p < 1024; p += 256) {
        int c = p >> 4, n4 = (p & 15) << 2;
        float4 r;
        r.x = T[c * 68 + n4 + 0];
        r.y = T[c * 68 + n4 + 1];
        r.z = T[c * 68 + n4 + 2];
        r.w = T[c * 68 + n4 + 3];
        *(float4*)&out[(((size_t)(b * 64 + c)) << 12) + n0 + n4] = r;
    }
}

// ---------------------------------------------------------------------------
extern "C" void kernel_launch(void* const* d_in, const int* in_sizes, int n_in,
                              void* d_out, int out_size, void* d_ws,
                              size_t ws_size, hipStream_t stream)
{
    const float* x    = (const float*)d_in[0];
    const float* c1w  = (const float*)d_in[1];
    const float* bn1g = (const float*)d_in[2];
    const float* bn1b = (const float*)d_in[3];
    const float* thw  = (const float*)d_in[4];
    const float* thb  = (const float*)d_in[5];
    const float* phw  = (const float*)d_in[6];
    const float* phb  = (const float*)d_in[7];
    const float* gw   = (const float*)d_in[8];
    const float* gb   = (const float*)d_in[9];
    const float* Wwt  = (const float*)d_in[10];
    const float* Wbs  = (const float*)d_in[11];
    const float* c2w  = (const float*)d_in[12];
    const float* bn2g = (const float*)d_in[13];
    const float* bn2b = (const float*)d_in[14];
    float* out = (float*)d_out;

    float* ws = (float*)d_ws;
    // region A: xT/x1T hi+lo -> O0 fp32 -> zT hi+lo
    ushort* xT_hi = (ushort*)ws;
    ushort* xT_lo = xT_hi + (1 << 20);
    ushort* x1T_hi = xT_hi;
    ushort* x1T_lo = xT_lo;
    float* O0 = ws;
    ushort* zT_hi = xT_hi;
    ushort* zT_lo = xT_lo;
    // region B: c1T fp32 -> O1 fp32 -> c2T fp32
    float* c1T = ws + (1 << 20);
    float* O1 = c1T;
    float* c2T = c1T;
    // region C: thT hi/lo -> yT hi/lo
    ushort* thT_hi = (ushort*)(ws + (2 << 20));
    ushort* thT_lo = thT_hi + (1 << 20);
    ushort* yT_hi = thT_hi;
    ushort* yT_lo = thT_lo;
    // regions D/E
    ushort* phT_hi = (ushort*)(ws + (3 << 20));
    ushort* phT_lo = phT_hi + (1 << 20);
    ushort* g16 = (ushort*)(ws + (4 << 20));
    // weights / partials / stats
    ushort* wp = (ushort*)(ws + (9 << 19));
    float* part = ws + (5 << 20) - 65536;
    float* stats = ws + (5 << 20);
    float* sc1 = stats, *sh1 = stats + 64, *sc2 = stats + 128, *sh2 = stats + 192;

    ushort* wc1h = wp;                ushort* wc1l = wc1h + 36864;
    ushort* wthh = wp + 1 * 73728;    ushort* wthl = wthh + 36864;
    ushort* wphh = wp + 2 * 73728;    ushort* wphl = wphh + 36864;
    ushort* wgh  = wp + 3 * 73728;    ushort* wgl  = wgh + 36864;
    ushort* wc2h = wp + 4 * 73728;    ushort* wc2l = wc2h + 36864;
    ushort* w11h = wp + 5 * 73728;    ushort* w11l = w11h + 4096;

    prep_all_k<<<992, 256, 0, stream>>>(x, xT_hi, xT_lo, c1w, thw, phw, gw,
                                        c2w, Wwt, wp);
    conv_mfma_k<1, 0><<<512, 256, 0, stream>>>(
        xT_hi, xT_lo, wc1h, wc1l, nullptr, nullptr, nullptr, nullptr,
        nullptr, nullptr, nullptr, c1T, part, nullptr, nullptr, nullptr,
        nullptr, nullptr);
    statsB_k<<<1, 256, 0, stream>>>(part, bn1g, bn1b, sc1, sh1);
    x1prep_k<<<1024, 256, 0, stream>>>(c1T, sc1, sh1, x1T_hi, x1T_lo);
    conv_mfma_k<3, 1><<<512, 256, 0, stream>>>(
        x1T_hi, x1T_lo, wthh, wthl, wphh, wphl, wgh, wgl, thb, phb, gb,
        nullptr, nullptr, thT_hi, thT_lo, phT_hi, phT_lo, g16);
    attn_k<<<512, 256, 0, stream>>>(thT_hi, thT_lo, phT_hi, phT_lo, g16,
                                    O0, O1, part);
    reduce_k<<<1024, 256, 0, stream>>>(O0, O1, part, yT_hi, yT_lo);
    conv1x1_k<<<512, 256, 0, stream>>>(yT_hi, yT_lo, w11h, w11l, Wbs, x,
                                       zT_hi, zT_lo);
    conv_mfma_k<1, 0><<<512, 256, 0, stream>>>(
        zT_hi, zT_lo, wc2h, wc2l, nullptr, nullptr, nullptr, nullptr,
        nullptr, nullptr, nullptr, c2T, part, nullptr, nullptr, nullptr,
        nullptr, nullptr);
    statsB_k<<<1, 256, 0, stream>>>(part, bn2g, bn2b, sc2, sh2);
    bnreluT_k<<<256, 256, 0, stream>>>(c2T, sc2, sh2, out);
}

// Round 7
// 267.343 us; speedup vs baseline: 1.5621x; 1.1118x over previous
//
#include <hip/hip_runtime.h>
#include <math.h>

// B=4, C=64, H=W=64, N=4096, NPIX=16384. All fp32 in/out.
// Pixel-major [pix][ch] bf16 hi/lo pipeline. ws (floats), footprint 5M+256:
//  A ws+0..1M   : xT hi/lo -> x1T hi/lo -> O0 (attn partial fp32) -> c2T fp32
//  B ws+1M..2M  : c1T fp32 -> O1 (attn partial fp32)
//  C ws+2M..3M  : thT hi/lo -> zT hi/lo
//  D ws+3M..4M  : phT hi/lo
//  E ws+4M..4.5M: g16 (bf16 [B][C][N])
//  wp ws+4.5M   : prepped weights ; part/lp ws+5M-65536 ; stats ws+5M

typedef __attribute__((ext_vector_type(8))) short short8;
typedef __attribute__((ext_vector_type(4))) float f32x4;

__device__ __forceinline__ ushort f2bf(float x) {
    unsigned u = __float_as_uint(x);
    unsigned r = (u + 0x7FFFu + ((u >> 16) & 1u)) >> 16;  // RNE
    return (ushort)r;
}
__device__ __forceinline__ float bf2f(ushort h) {
    return __uint_as_float(((unsigned)h) << 16);
}

// ---------------------------------------------------------------------------
// prep_all: blocks <256: x -> xT [pix][ch] bf16 hi/lo. blocks >=256: weights.
// ---------------------------------------------------------------------------
__global__ __launch_bounds__(256) void prep_all_k(
    const float* __restrict__ x, ushort* __restrict__ xh,
    ushort* __restrict__ xl,
    const float* __restrict__ w0, const float* __restrict__ w1,
    const float* __restrict__ w2, const float* __restrict__ w3,
    const float* __restrict__ w4, const float* __restrict__ w5,
    ushort* __restrict__ wbase)
{
    __shared__ __align__(16) float T[64 * 68];
    const int blk = blockIdx.x, t = threadIdx.x;
    if (blk < 256) {
        const int b = blk >> 6, n0 = (blk & 63) << 6;
        for (int p = t; p < 1024; p += 256) {
            int c = p >> 4, n4 = (p & 15) << 2;
            *(float4*)&T[c * 68 + n4] =
                *(const float4*)&x[(((size_t)(b * 64 + c)) << 12) + n0 + n4];
        }
        __syncthreads();
        for (int p = t; p < 1024; p += 256) {
            int n = p >> 4, c4 = (p & 15) << 2;
            size_t off = (((size_t)(b * 4096 + n0 + n)) << 6) + c4;
            ushort4 hi, lo;
            float v;
            v = T[(c4 + 0) * 68 + n]; hi.x = f2bf(v); lo.x = f2bf(v - bf2f(hi.x));
            v = T[(c4 + 1) * 68 + n]; hi.y = f2bf(v); lo.y = f2bf(v - bf2f(hi.y));
            v = T[(c4 + 2) * 68 + n]; hi.z = f2bf(v); lo.z = f2bf(v - bf2f(hi.z));
            v = T[(c4 + 3) * 68 + n]; hi.w = f2bf(v); lo.w = f2bf(v - bf2f(hi.w));
            *(ushort4*)&xh[off] = hi;
            *(ushort4*)&xl[off] = lo;
        }
    } else {
        const float* W[6] = {w0, w1, w2, w3, w4, w5};
        int q = blk - 256;
        if (q < 720) {
            int s = q / 144, bi = q - s * 144;
            int idx = bi * 256 + t;
            if (idx >= 36864) return;
            int co = idx / 576;
            int r = idx - co * 576;
            int ci = r / 9;
            int tap = r - ci * 9;
            float v = W[s][idx];
            ushort* hi = wbase + (size_t)s * 73728;
            ushort* lo = hi + 36864;
            int off = tap * 4096 + co * 64 + ci;
            ushort h = f2bf(v);
            hi[off] = h;
            lo[off] = f2bf(v - bf2f(h));
        } else {
            int idx = (q - 720) * 256 + t;
            if (idx >= 4096) return;
            float v = W[5][idx];
            ushort* hi = wbase + 5 * 73728;
            ushort* lo = hi + 4096;
            ushort h = f2bf(v);
            hi[idx] = h;
            lo[idx] = f2bf(v - bf2f(h));
        }
    }
}

// ---------------------------------------------------------------------------
// MFMA 3x3 conv, r3 geometry (proven): block = 64 pix (one h-row) x 64 co,
// grid 256, wave tile 32pix x 32co. hi/lo compensated (3 MFMA/product).
// MODE 0: fp32 out [pix][co] + fused BN partial stats -> part[blk*64+ch].
// MODE 1 (NOUT=3): theta/phi -> hi/lo [pix][co]; g -> bf16 [B][co][n].
// ---------------------------------------------------------------------------
template <int NOUT, int MODE>
__global__ __launch_bounds__(256) void conv_mfma_k(
    const ushort* __restrict__ Ah, const ushort* __restrict__ Al,
    const ushort* __restrict__ w0h, const ushort* __restrict__ w0l,
    const ushort* __restrict__ w1h, const ushort* __restrict__ w1l,
    const ushort* __restrict__ w2h, const ushort* __restrict__ w2l,
    const float* __restrict__ b0, const float* __restrict__ b1,
    const float* __restrict__ b2,
    float* __restrict__ outF, float* __restrict__ part,
    ushort* __restrict__ o0h, ushort* __restrict__ o0l,
    ushort* __restrict__ o1h, ushort* __restrict__ o1l,
    ushort* __restrict__ o2t)
{
    __shared__ float redS[4][32], redSS[4][32];
    const int t = threadIdx.x, lane = t & 63, wv = t >> 6;
    const int quad = lane >> 4, l15 = lane & 15;
    const int blk = blockIdx.x;  // b*64 + h
    const int h = blk & 63;
    const int P0 = blk << 6;
    const int rhalf = (wv >> 1) << 5, chalf = (wv & 1) << 5;

    const ushort* wh[3] = {w0h, w1h, w2h};
    const ushort* wl[3] = {w0l, w1l, w2l};

    f32x4 acc[NOUT][2][2];
#pragma unroll
    for (int o = 0; o < NOUT; ++o)
#pragma unroll
        for (int rb = 0; rb < 2; ++rb)
#pragma unroll
            for (int cb = 0; cb < 2; ++cb)
#pragma unroll
                for (int j = 0; j < 4; ++j) acc[o][rb][cb][j] = 0.f;

#pragma unroll
    for (int dh = -1; dh <= 1; ++dh) {
        if ((unsigned)(h + dh) >= 64u) continue;  // block-uniform
#pragma unroll
        for (int dw = -1; dw <= 1; ++dw) {
            const int tap = (dh + 1) * 3 + (dw + 1);
#pragma unroll
            for (int kc = 0; kc < 2; ++kc) {
                const int k0 = kc * 32 + quad * 8;
                short8 aH[2], aL[2];
#pragma unroll
                for (int rb = 0; rb < 2; ++rb) {
                    int wrow = rhalf + (rb << 4) + l15;
                    int sw = wrow + dw;
                    short8 z = {0, 0, 0, 0, 0, 0, 0, 0};
                    aH[rb] = z;
                    aL[rb] = z;
                    if ((unsigned)sw < 64u) {
                        int sp = P0 + dh * 64 + sw;
                        size_t off = (((size_t)sp) << 6) + k0;
                        aH[rb] = *(const short8*)&Ah[off];
                        aL[rb] = *(const short8*)&Al[off];
                    }
                }
#pragma unroll
                for (int o = 0; o < NOUT; ++o) {
#pragma unroll
                    for (int cb = 0; cb < 2; ++cb) {
                        int co = chalf + (cb << 4) + l15;
                        size_t woff = (((size_t)tap) << 12) + (((size_t)co) << 6) + k0;
                        short8 bH = *(const short8*)&wh[o][woff];
                        short8 bL = *(const short8*)&wl[o][woff];
#pragma unroll
                        for (int rb = 0; rb < 2; ++rb) {
                            acc[o][rb][cb] = __builtin_amdgcn_mfma_f32_16x16x32_bf16(
                                aH[rb], bH, acc[o][rb][cb], 0, 0, 0);
                            acc[o][rb][cb] = __builtin_amdgcn_mfma_f32_16x16x32_bf16(
                                aH[rb], bL, acc[o][rb][cb], 0, 0, 0);
                            acc[o][rb][cb] = __builtin_amdgcn_mfma_f32_16x16x32_bf16(
                                aL[rb], bH, acc[o][rb][cb], 0, 0, 0);
                        }
                    }
                }
            }
        }
    }

    if (MODE == 0) {
        float s_[2], ss_[2];
#pragma unroll
        for (int cb = 0; cb < 2; ++cb) {
            int co = chalf + (cb << 4) + l15;
            float s = 0.f, ss = 0.f;
#pragma unroll
            for (int rb = 0; rb < 2; ++rb)
#pragma unroll
                for (int r = 0; r < 4; ++r) {
                    int pix = P0 + rhalf + (rb << 4) + (quad << 2) + r;
                    float v = acc[0][rb][cb][r];
                    outF[(((size_t)pix) << 6) + co] = v;
                    s += v;
                    ss += v * v;
                }
            s_[cb] = s;
            ss_[cb] = ss;
        }
#pragma unroll
        for (int off = 16; off < 64; off <<= 1) {
#pragma unroll
            for (int cb = 0; cb < 2; ++cb) {
                s_[cb] += __shfl_xor(s_[cb], off);
                ss_[cb] += __shfl_xor(ss_[cb], off);
            }
        }
        if (quad == 0) {
#pragma unroll
            for (int cb = 0; cb < 2; ++cb) {
                redS[wv][(cb << 4) + l15] = s_[cb];
                redSS[wv][(cb << 4) + l15] = ss_[cb];
            }
        }
        __syncthreads();
        if (t < 64) {
            int w01 = (t >> 5) & 1;  // chalf bit
            float S = redS[w01][t & 31] + redS[w01 + 2][t & 31];
            float SS = redSS[w01][t & 31] + redSS[w01 + 2][t & 31];
            part[blk * 64 + t] = S;
            part[16384 + blk * 64 + t] = SS;
        }
    } else {
        const int b = P0 >> 12;
#pragma unroll
        for (int rb = 0; rb < 2; ++rb)
#pragma unroll
            for (int cb = 0; cb < 2; ++cb) {
                int co = chalf + (cb << 4) + l15;
                float bth = b0[co], bph = b1[co], bg = b2[co];
                int pixb = P0 + rhalf + (rb << 4) + (quad << 2);
#pragma unroll
                for (int r = 0; r < 4; ++r) {
                    size_t off = (((size_t)(pixb + r)) << 6) + co;
                    float v = acc[0][rb][cb][r] + bth;
                    ushort hh = f2bf(v);
                    o0h[off] = hh;
                    o0l[off] = f2bf(v - bf2f(hh));
                    v = acc[1][rb][cb][r] + bph;
                    hh = f2bf(v);
                    o1h[off] = hh;
                    o1l[off] = f2bf(v - bf2f(hh));
                }
                int n0 = pixb & 4095;
                ushort4 gv;
                gv.x = f2bf(acc[2][rb][cb][0] + bg);
                gv.y = f2bf(acc[2][rb][cb][1] + bg);
                gv.z = f2bf(acc[2][rb][cb][2] + bg);
                gv.w = f2bf(acc[2][rb][cb][3] + bg);
                *(ushort4*)&o2t[(((size_t)b) << 18) + (((size_t)co) << 12) + n0] = gv;
            }
    }
}

// ---------------------------------------------------------------------------
// statsB: reduce 256 block-partials per channel -> BN scale/shift.
// ---------------------------------------------------------------------------
__global__ __launch_bounds__(256) void statsB_k(
    const float* __restrict__ part, const float* __restrict__ gamma,
    const float* __restrict__ beta, float* __restrict__ scale,
    float* __restrict__ shift)
{
    __shared__ float rs[4][64], rss[4][64];
    const int t = threadIdx.x, c = t & 63, seg = t >> 6;
    float S = 0.f, SS = 0.f;
    for (int k = seg * 64; k < seg * 64 + 64; ++k) {
        S += part[k * 64 + c];
        SS += part[16384 + k * 64 + c];
    }
    rs[seg][c] = S;
    rss[seg][c] = SS;
    __syncthreads();
    if (t < 64) {
        float Sf = rs[0][t] + rs[1][t] + rs[2][t] + rs[3][t];
        float SSf = rss[0][t] + rss[1][t] + rss[2][t] + rss[3][t];
        float mean = Sf * (1.f / 16384.f);
        float var = SSf * (1.f / 16384.f) - mean * mean;
        float sc = gamma[t] * rsqrtf(var + 1e-5f);
        scale[t] = sc;
        shift[t] = beta[t] - mean * sc;
    }
}

// ---------------------------------------------------------------------------
// x1prep: c1T fp32 [pix][ch] -> relu(BN) -> x1T bf16 hi/lo.
// ---------------------------------------------------------------------------
__global__ __launch_bounds__(256) void x1prep_k(
    const float* __restrict__ c1T, const float* __restrict__ sc,
    const float* __restrict__ sh, ushort* __restrict__ xh,
    ushort* __restrict__ xl)
{
    int p = blockIdx.x * 256 + threadIdx.x;  // < 262144
    int c4 = (p & 15) << 2;
    float4 v = *(const float4*)&c1T[(size_t)p << 2];
    float4 s4 = *(const float4*)&sc[c4];
    float4 h4 = *(const float4*)&sh[c4];
    float r0 = fmaxf(v.x * s4.x + h4.x, 0.f);
    float r1 = fmaxf(v.y * s4.y + h4.y, 0.f);
    float r2 = fmaxf(v.z * s4.z + h4.z, 0.f);
    float r3 = fmaxf(v.w * s4.w + h4.w, 0.f);
    ushort4 hi, lo;
    hi.x = f2bf(r0); lo.x = f2bf(r0 - bf2f(hi.x));
    hi.y = f2bf(r1); lo.y = f2bf(r1 - bf2f(hi.y));
    hi.z = f2bf(r2); lo.z = f2bf(r2 - bf2f(hi.z));
    hi.w = f2bf(r3); lo.w = f2bf(r3 - bf2f(hi.w));
    *(ushort4*)&xh[(size_t)p << 2] = hi;
    *(ushort4*)&xl[(size_t)p << 2] = lo;
}

// ---------------------------------------------------------------------------
// Flash attention, round-5 proven structure (bf16 P via swizzled LDS, K=32
// PV, static max M=30, LDS staging + register prefetch, 2-way KV split,
// XCD swizzle) with ONE change: Q fragments are hoisted into registers,
// loaded directly from global once (they are step-invariant) -- removes
// 8 b128 LDS reads/step and the 16 KB Q LDS. Partial O fp32 + partial l out.
// ---------------------------------------------------------------------------
__device__ __forceinline__ short8 ldfrag(const ushort* base, int row, int ch) {
    return *(const short8*)&base[(row << 6) + (((ch ^ (row & 7))) << 3)];
}

__global__ __launch_bounds__(256) void attn_k(
    const ushort* __restrict__ thT_hi, const ushort* __restrict__ thT_lo,
    const ushort* __restrict__ phT_hi, const ushort* __restrict__ phT_lo,
    const ushort* __restrict__ g16, float* __restrict__ O0,
    float* __restrict__ O1, float* __restrict__ lp)
{
    __shared__ __align__(16) ushort Khi[4096], Klo[4096];
    __shared__ __align__(16) ushort Vt[2][4096];
    __shared__ __align__(16) ushort Pt[4096];

    const int t = threadIdx.x;
    const int bx = blockIdx.x;
    const int xslot = bx & 7;
    const int b = xslot & 3;
    const int half = xslot >> 2;
    const int q0 = (bx >> 3) << 6;
    const int mbase = half << 11;
    const int lane = t & 63;
    const int wv = t >> 6;
    const int quad = lane >> 4;
    const int l15 = lane & 15;
    const int rhalf = (wv >> 1) << 5;
    const int chalf = (wv & 1) << 5;

    const size_t cb64 = ((size_t)b) << 18;
    const ushort* Qh_g = thT_hi + cb64 + (((size_t)q0) << 6);
    const ushort* Ql_g = thT_lo + cb64 + (((size_t)q0) << 6);
    const ushort* Kh_g = phT_hi + cb64;
    const ushort* Kl_g = phT_lo + cb64;
    const ushort* Vg = g16 + cb64;
    float* Op = half ? O1 : O0;
    float* lpd = lp + (half << 14);

    // hoisted Q A-frags straight from global (step-invariant)
    short8 aHi[2][2], aLo[2][2];
#pragma unroll
    for (int rb = 0; rb < 2; ++rb)
#pragma unroll
        for (int ks = 0; ks < 2; ++ks) {
            size_t off = (((size_t)(rhalf + (rb << 4) + l15)) << 6) +
                         ks * 32 + quad * 8;
            aHi[rb][ks] = *(const short8*)&Qh_g[off];
            aLo[rb][ks] = *(const short8*)&Ql_g[off];
        }

    // initial staging: step-0 K/V
#pragma unroll
    for (int rd = 0; rd < 2; ++rd) {
        int ii = rd * 256 + t;
        int row = ii >> 3, ch = ii & 7;
        int off = (row << 6) + ((ch ^ (row & 7)) << 3);
        *(short8*)&Khi[off] = *(const short8*)&Kh_g[((mbase + row) << 6) + (ch << 3)];
        *(short8*)&Klo[off] = *(const short8*)&Kl_g[((mbase + row) << 6) + (ch << 3)];
        *(short8*)&Vt[0][off] = *(const short8*)&Vg[(row << 12) + mbase + (ch << 3)];
    }

    f32x4 oacc[2][2];
    f32x4 lacc[2];
#pragma unroll
    for (int rb = 0; rb < 2; ++rb) {
#pragma unroll
        for (int j = 0; j < 4; ++j) lacc[rb][j] = 0.f;
#pragma unroll
        for (int cb = 0; cb < 2; ++cb)
#pragma unroll
            for (int j = 0; j < 4; ++j) oacc[rb][cb][j] = 0.f;
    }
    short8 onesB;
    {
        short ov = (l15 == 0) ? (short)0x3F80 : (short)0;
#pragma unroll
        for (int j = 0; j < 8; ++j) onesB[j] = ov;
    }

    for (int step = 0; step < 32; ++step) {
        const int buf = step & 1;
        __syncthreads();  // K/V(step) visible; P(step-1) consumers done

        short8 rKh[2], rKl[2], rV[2];
        if (step < 31) {
            const int m1 = mbase + ((step + 1) << 6);
#pragma unroll
            for (int rd = 0; rd < 2; ++rd) {
                int ii = rd * 256 + t;
                int row = ii >> 3, ch = ii & 7;
                rKh[rd] = *(const short8*)&Kh_g[((m1 + row) << 6) + (ch << 3)];
                rKl[rd] = *(const short8*)&Kl_g[((m1 + row) << 6) + (ch << 3)];
                rV[rd] = *(const short8*)&Vg[(row << 12) + m1 + (ch << 3)];
            }
        }

        short8 bHi[2][2], bLo[2][2];
#pragma unroll
        for (int cb = 0; cb < 2; ++cb) {
            int row = chalf + (cb << 4) + l15;
#pragma unroll
            for (int ks = 0; ks < 2; ++ks) {
                bHi[cb][ks] = ldfrag(Khi, row, (ks << 2) + quad);
                bLo[cb][ks] = ldfrag(Klo, row, (ks << 2) + quad);
            }
        }
        f32x4 sacc[2][2];
#pragma unroll
        for (int rb = 0; rb < 2; ++rb)
#pragma unroll
            for (int cb = 0; cb < 2; ++cb)
#pragma unroll
                for (int j = 0; j < 4; ++j) sacc[rb][cb][j] = 0.f;
#pragma unroll
        for (int ks = 0; ks < 2; ++ks)
#pragma unroll
            for (int rb = 0; rb < 2; ++rb)
#pragma unroll
                for (int cb = 0; cb < 2; ++cb) {
                    sacc[rb][cb] = __builtin_amdgcn_mfma_f32_16x16x32_bf16(
                        aHi[rb][ks], bHi[cb][ks], sacc[rb][cb], 0, 0, 0);
                    sacc[rb][cb] = __builtin_amdgcn_mfma_f32_16x16x32_bf16(
                        aHi[rb][ks], bLo[cb][ks], sacc[rb][cb], 0, 0, 0);
                    sacc[rb][cb] = __builtin_amdgcn_mfma_f32_16x16x32_bf16(
                        aLo[rb][ks], bHi[cb][ks], sacc[rb][cb], 0, 0, 0);
                }
#pragma unroll
        for (int rb = 0; rb < 2; ++rb)
#pragma unroll
            for (int cb = 0; cb < 2; ++cb) {
                int pcol = chalf + (cb << 4) + l15;
#pragma unroll
                for (int r = 0; r < 4; ++r) {
                    int prow = rhalf + (rb << 4) + (quad << 2) + r;
                    float p = __expf(sacc[rb][cb][r] - 30.f);
                    Pt[(prow << 6) + (((pcol >> 3) ^ (prow & 7)) << 3) +
                       (pcol & 7)] = f2bf(p);
                }
            }
        __syncthreads();  // P visible; all S-phase K reads done

        short8 pa[2][2], vb[2][2];
#pragma unroll
        for (int rb = 0; rb < 2; ++rb) {
            int row = rhalf + (rb << 4) + l15;
#pragma unroll
            for (int ks = 0; ks < 2; ++ks)
                pa[rb][ks] = ldfrag(Pt, row, (ks << 2) + quad);
        }
#pragma unroll
        for (int cb = 0; cb < 2; ++cb) {
            int row = chalf + (cb << 4) + l15;
#pragma unroll
            for (int ks = 0; ks < 2; ++ks)
                vb[cb][ks] = ldfrag(&Vt[buf][0], row, (ks << 2) + quad);
        }
#pragma unroll
        for (int ks = 0; ks < 2; ++ks)
#pragma unroll
            for (int rb = 0; rb < 2; ++rb)
#pragma unroll
                for (int cb = 0; cb < 2; ++cb)
                    oacc[rb][cb] = __builtin_amdgcn_mfma_f32_16x16x32_bf16(
                        pa[rb][ks], vb[cb][ks], oacc[rb][cb], 0, 0, 0);
#pragma unroll
        for (int rb = 0; rb < 2; ++rb)
#pragma unroll
            for (int ks = 0; ks < 2; ++ks)
                lacc[rb] = __builtin_amdgcn_mfma_f32_16x16x32_bf16(
                    pa[rb][ks], onesB, lacc[rb], 0, 0, 0);

        if (step < 31) {
#pragma unroll
            for (int rd = 0; rd < 2; ++rd) {
                int ii = rd * 256 + t;
                int row = ii >> 3, ch = ii & 7;
                int off = (row << 6) + ((ch ^ (row & 7)) << 3);
                *(short8*)&Khi[off] = rKh[rd];
                *(short8*)&Klo[off] = rKl[rd];
                *(short8*)&Vt[buf ^ 1][off] = rV[rd];
            }
        }
    }

    // epilogue: write partial l (col-0 lanes) and partial O (no division)
#pragma unroll
    for (int rb = 0; rb < 2; ++rb) {
        if ((wv & 1) == 0 && l15 == 0) {
#pragma unroll
            for (int r = 0; r < 4; ++r) {
                int nn = q0 + rhalf + (rb << 4) + (quad << 2) + r;
                lpd[(b << 12) + nn] = lacc[rb][r];
            }
        }
#pragma unroll
        for (int cb = 0; cb < 2; ++cb) {
            int cc = chalf + (cb << 4) + l15;
#pragma unroll
            for (int r = 0; r < 4; ++r) {
                int nn = q0 + rhalf + (rb << 4) + (quad << 2) + r;
                Op[cb64 + (((size_t)nn) << 6) + cc] = oacc[rb][cb][r];
            }
        }
    }
}

// ---------------------------------------------------------------------------
// 1x1 conv + bias + residual, MFMA, with FUSED attention reduce:
// y = (O0+O1)/(l0+l1) built in-register as bf16 hi/lo A-frags.
// ---------------------------------------------------------------------------
__global__ __launch_bounds__(256) void conv1x1_k(
    const float* __restrict__ O0, const float* __restrict__ O1,
    const float* __restrict__ lp,
    const ushort* __restrict__ wh, const ushort* __restrict__ wl,
    const float* __restrict__ Wb, const float* __restrict__ x,
    ushort* __restrict__ zh, ushort* __restrict__ zl)
{
    const int t = threadIdx.x, lane = t & 63, wv = t >> 6;
    const int quad = lane >> 4, l15 = lane & 15;
    const int chalf = (wv & 1) << 5;
    const int P0 = blockIdx.x << 5;
    const int pbase = P0 + ((wv >> 1) << 4);
    const int b = P0 >> 12;
    const int pix = pbase + l15;   // A row
    const int nn = pix & 4095;
    const float linv = 1.f / (lp[(b << 12) + nn] + lp[16384 + (b << 12) + nn]);

    f32x4 acc[2];
#pragma unroll
    for (int j = 0; j < 4; ++j) { acc[0][j] = 0.f; acc[1][j] = 0.f; }

#pragma unroll
    for (int kc = 0; kc < 2; ++kc) {
        const int k0 = kc * 32 + quad * 8;
        size_t ao = (((size_t)pix) << 6) + k0;
        float4 a0 = *(const float4*)&O0[ao];
        float4 a1 = *(const float4*)&O0[ao + 4];
        float4 c0 = *(const float4*)&O1[ao];
        float4 c1 = *(const float4*)&O1[ao + 4];
        float v[8] = {(a0.x + c0.x) * linv, (a0.y + c0.y) * linv,
                      (a0.z + c0.z) * linv, (a0.w + c0.w) * linv,
                      (a1.x + c1.x) * linv, (a1.y + c1.y) * linv,
                      (a1.z + c1.z) * linv, (a1.w + c1.w) * linv};
        short8 aH, aL;
#pragma unroll
        for (int j = 0; j < 8; ++j) {
            ushort hh = f2bf(v[j]);
            aH[j] = (short)hh;
            aL[j] = (short)f2bf(v[j] - bf2f(hh));
        }
#pragma unroll
        for (int cb = 0; cb < 2; ++cb) {
            int co = chalf + (cb << 4) + l15;
            short8 bH = *(const short8*)&wh[(((size_t)co) << 6) + k0];
            short8 bL = *(const short8*)&wl[(((size_t)co) << 6) + k0];
            acc[cb] = __builtin_amdgcn_mfma_f32_16x16x32_bf16(aH, bH, acc[cb], 0, 0, 0);
            acc[cb] = __builtin_amdgcn_mfma_f32_16x16x32_bf16(aH, bL, acc[cb], 0, 0, 0);
            acc[cb] = __builtin_amdgcn_mfma_f32_16x16x32_bf16(aL, bH, acc[cb], 0, 0, 0);
        }
    }

    const int pixb = pbase + (quad << 2);
    const int n0 = pixb & 4095;
#pragma unroll
    for (int cb = 0; cb < 2; ++cb) {
        int co = chalf + (cb << 4) + l15;
        float bias = Wb[co];
        float4 xr = *(const float4*)&x[(((size_t)(b * 64 + co)) << 12) + n0];
        float xa[4] = {xr.x, xr.y, xr.z, xr.w};
#pragma unroll
        for (int r = 0; r < 4; ++r) {
            float v = acc[cb][r] + bias + xa[r];
            size_t off = (((size_t)(pixb + r)) << 6) + co;
            ushort hh = f2bf(v);
            zh[off] = hh;
            zl[off] = f2bf(v - bf2f(hh));
        }
    }
}

// ---------------------------------------------------------------------------
// Final: BN2 apply + relu + transpose back to [B][C][H][W].
// ---------------------------------------------------------------------------
__global__ __launch_bounds__(256) void bnreluT_k(
    const float* __restrict__ c2T, const float* __restrict__ sc,
    const float* __restrict__ sh, float* __restrict__ out)
{
    __shared__ __align__(16) float T[64 * 68];
    const int b = blockIdx.x >> 6, n0 = (blockIdx.x & 63) << 6, t = threadIdx.x;
    for (int p = t; p < 1024; p += 256) {
        int n = p >> 4, c4 = (p & 15) << 2;
        float4 v = *(const float4*)&c2T[(((size_t)(b * 4096 + n0 + n)) << 6) + c4];
        float4 s4 = *(const float4*)&sc[c4];
        float4 h4 = *(const float4*)&sh[c4];
        T[(c4 + 0) * 68 + n] = fmaxf(v.x * s4.x + h4.x, 0.f);
        T[(c4 + 1) * 68 + n] = fmaxf(v.y * s4.y + h4.y, 0.f);
        T[(c4 + 2) * 68 + n] = fmaxf(v.z * s4.z + h4.z, 0.f);
        T[(c4 + 3) * 68 + n] = fmaxf(v.w * s4.w + h4.w, 0.f);
    }
    __syncthreads();
    for (int p = t; p < 1024; p += 256) {
        int c = p >> 4, n4 = (p & 15) << 2;
        float4 r;
        r.x = T[c * 68 + n4 + 0];
        r.y = T[c * 68 + n4 + 1];
        r.z = T[c * 68 + n4 + 2];
        r.w = T[c * 68 + n4 + 3];
        *(float4*)&out[(((size_t)(b * 64 + c)) << 12) + n0 + n4] = r;
    }
}

// ---------------------------------------------------------------------------
extern "C" void kernel_launch(void* const* d_in, const int* in_sizes, int n_in,
                              void* d_out, int out_size, void* d_ws,
                              size_t ws_size, hipStream_t stream)
{
    const float* x    = (const float*)d_in[0];
    const float* c1w  = (const float*)d_in[1];
    const float* bn1g = (const float*)d_in[2];
    const float* bn1b = (const float*)d_in[3];
    const float* thw  = (const float*)d_in[4];
    const float* thb  = (const float*)d_in[5];
    const float* phw  = (const float*)d_in[6];
    const float* phb  = (const float*)d_in[7];
    const float* gw   = (const float*)d_in[8];
    const float* gb   = (const float*)d_in[9];
    const float* Wwt  = (const float*)d_in[10];
    const float* Wbs  = (const float*)d_in[11];
    const float* c2w  = (const float*)d_in[12];
    const float* bn2g = (const float*)d_in[13];
    const float* bn2b = (const float*)d_in[14];
    float* out = (float*)d_out;

    float* ws = (float*)d_ws;
    // region A: xT/x1T hi+lo -> O0 fp32 -> c2T fp32
    ushort* xT_hi = (ushort*)ws;
    ushort* xT_lo = xT_hi + (1 << 20);
    ushort* x1T_hi = xT_hi;
    ushort* x1T_lo = xT_lo;
    float* O0 = ws;
    float* c2T = ws;
    // region B: c1T fp32 -> O1 fp32
    float* c1T = ws + (1 << 20);
    float* O1 = c1T;
    // region C: thT hi/lo -> zT hi/lo
    ushort* thT_hi = (ushort*)(ws + (2 << 20));
    ushort* thT_lo = thT_hi + (1 << 20);
    ushort* zT_hi = thT_hi;
    ushort* zT_lo = thT_lo;
    // regions D/E
    ushort* phT_hi = (ushort*)(ws + (3 << 20));
    ushort* phT_lo = phT_hi + (1 << 20);
    ushort* g16 = (ushort*)(ws + (4 << 20));
    // weights / partials / stats
    ushort* wp = (ushort*)(ws + (9 << 19));
    float* part = ws + (5 << 20) - 65536;  // also lp for attention
    float* stats = ws + (5 << 20);
    float* sc1 = stats, *sh1 = stats + 64, *sc2 = stats + 128, *sh2 = stats + 192;

    ushort* wc1h = wp;                ushort* wc1l = wc1h + 36864;
    ushort* wthh = wp + 1 * 73728;    ushort* wthl = wthh + 36864;
    ushort* wphh = wp + 2 * 73728;    ushort* wphl = wphh + 36864;
    ushort* wgh  = wp + 3 * 73728;    ushort* wgl  = wgh + 36864;
    ushort* wc2h = wp + 4 * 73728;    ushort* wc2l = wc2h + 36864;
    ushort* w11h = wp + 5 * 73728;    ushort* w11l = w11h + 4096;

    prep_all_k<<<992, 256, 0, stream>>>(x, xT_hi, xT_lo, c1w, thw, phw, gw,
                                        c2w, Wwt, wp);
    conv_mfma_k<1, 0><<<256, 256, 0, stream>>>(
        xT_hi, xT_lo, wc1h, wc1l, nullptr, nullptr, nullptr, nullptr,
        nullptr, nullptr, nullptr, c1T, part, nullptr, nullptr, nullptr,
        nullptr, nullptr);
    statsB_k<<<1, 256, 0, stream>>>(part, bn1g, bn1b, sc1, sh1);
    x1prep_k<<<1024, 256, 0, stream>>>(c1T, sc1, sh1, x1T_hi, x1T_lo);
    conv_mfma_k<3, 1><<<256, 256, 0, stream>>>(
        x1T_hi, x1T_lo, wthh, wthl, wphh, wphl, wgh, wgl, thb, phb, gb,
        nullptr, nullptr, thT_hi, thT_lo, phT_hi, phT_lo, g16);
    attn_k<<<512, 256, 0, stream>>>(thT_hi, thT_lo, phT_hi, phT_lo, g16,
                                    O0, O1, part);
    conv1x1_k<<<512, 256, 0, stream>>>(O0, O1, part, w11h, w11l, Wbs, x,
                                       zT_hi, zT_lo);
    conv_mfma_k<1, 0><<<256, 256, 0, stream>>>(
        zT_hi, zT_lo, wc2h, wc2l, nullptr, nullptr, nullptr, nullptr,
        nullptr, nullptr, nullptr, c2T, part, nullptr, nullptr, nullptr,
        nullptr, nullptr);
    statsB_k<<<1, 256, 0, stream>>>(part, bn2g, bn2b, sc2, sh2);
    bnreluT_k<<<256, 256, 0, stream>>>(c2T, sc2, sh2, out);
}